// Round 8
// baseline (143.488 us; speedup 1.0000x reference)
//
#include <hip/hip_runtime.h>
#include <math.h>

// ---------------------------------------------------------------------------
// GeoFeatureExtractor: B=256, T=512, N=51 landmarks x 3 (fp32), 114 features.
// Round 13 == Round 12 resubmit (two consecutive container infra failures;
// kernel never ran; vmcnt ledger re-audited, no defect found).
// r12: counted-vmcnt pipeline. r11 post-mortem: residency 4->8->16 waves/CU
// moved time 56->49.7->48 us — occupancy was never binding. The kernel was
// bulk-synchronous: vmcnt(0) drain -> compute -> store gives HBM a ~35% duty
// cycle (hbm_gbps pinned at 2.2 TB/s vs 6.6 for fillBuffer).
// Fix (guide T3/T4): persistent blocks over NT=4 consecutive tiles, S[2]
// double-buffer, raw s_barrier + COUNTED s_waitcnt vmcnt(N) (10/18/18/8 —
// never 0 in the loop) so tile k+2's DMA stays in flight across barriers.
// All VMEM is explicit builtins with uniform per-wave counts (10 staging/
// tile, 8 stores/tile; masks+halos duplicated across waves in prologue).
// LDS 40.8 KB -> 4 blocks/CU; grid 1024 = exactly 4/CU, no tail.
// Kept: 2-wave GEOM/ANGLE role split, linear width-16 global_load_lds,
// LDS out-image + coalesced float4 burst, Hastings acos, v_rcp/v_sqrt.
// ---------------------------------------------------------------------------

#define NF   114
#define NC   153
#define TILE 32                  // timesteps per tile
#define NT   4                   // tiles per block
#define TPB  (TILE * NT)         // 128 timesteps per block
#define SFLOATS (TILE * NC)      // 4896 floats per tile (19,584 B)

#if defined(__has_builtin)
#if __has_builtin(__builtin_amdgcn_global_load_lds)
#define USE_DMA 1
#endif
#endif
#ifndef USE_DMA
#define USE_DMA 0
#endif

typedef const __attribute__((address_space(1))) void gas_t;
typedef __attribute__((address_space(3))) void las_t;

// width-16 DMA: per-lane global addr g; LDS dest = wave-uniform base + lane*16
__device__ __forceinline__ void dma16(const float* g, float* lds) {
#if USE_DMA
    __builtin_amdgcn_global_load_lds((gas_t*)g, (las_t*)lds, 16, 0, 0);
#else
    *reinterpret_cast<float4*>(lds + (threadIdx.x & 63) * 4) =
        *reinterpret_cast<const float4*>(g);
#endif
}
// width-4 DMA: LDS dest = wave-uniform base + lane*4
__device__ __forceinline__ void dma4(const float* g, float* lds) {
#if USE_DMA
    __builtin_amdgcn_global_load_lds((gas_t*)g, (las_t*)lds, 4, 0, 0);
#else
    lds[threadIdx.x & 63] = *g;
#endif
}

struct V3 { float x, y, z; };

__device__ __forceinline__ V3 operator-(V3 a, V3 b) { return {a.x - b.x, a.y - b.y, a.z - b.z}; }
__device__ __forceinline__ V3 operator+(V3 a, V3 b) { return {a.x + b.x, a.y + b.y, a.z + b.z}; }
__device__ __forceinline__ V3 operator*(V3 a, float s) { return {a.x * s, a.y * s, a.z * s}; }
__device__ __forceinline__ float dot3(V3 a, V3 b) { return a.x * b.x + a.y * b.y + a.z * b.z; }
__device__ __forceinline__ V3 cross3(V3 a, V3 b) {
    return {a.y * b.z - a.z * b.y, a.z * b.x - a.x * b.z, a.x * b.y - a.y * b.x};
}

__device__ __forceinline__ float fsqrt(float x) { return __builtin_amdgcn_sqrtf(x); }
__device__ __forceinline__ float frcp(float x)  { return __builtin_amdgcn_rcpf(x); }

__device__ __forceinline__ float norm3(V3 a) { return fsqrt(dot3(a, a)); }
__device__ __forceinline__ float dist3(V3 a, V3 b) { V3 d = a - b; return fsqrt(dot3(d, d) + 1e-6f); }

// clip + Hastings acos approximation, |err| < 7e-5 rad
__device__ __forceinline__ float acosc(float c) {
    c = fminf(fmaxf(c, -1.0f + 1e-6f), 1.0f - 1e-6f);
    float ax = fabsf(c);
    float r = fsqrt(1.0f - ax) *
              (1.5707288f + ax * (-0.2121144f + ax * (0.0742610f - 0.0187293f * ax)));
    return c < 0.0f ? 3.14159265358979f - r : r;
}

// boundary-mapped central-diff endpoints (exact _cdiff semantics)
__device__ __forceinline__ void bmap(int tt, int T, int& ta, int& tb) {
    if (tt == 0)          { ta = 0;      tb = 2;     }
    else if (tt == T - 1) { ta = T - 3;  tb = T - 1; }
    else                  { ta = tt - 1; tb = tt + 1; }
}

__global__ __launch_bounds__(128, 4) void geo_fused(
    const float* __restrict__ xyz,
    const float* __restrict__ fmask,
    const float* __restrict__ bmask,
    float* __restrict__ out,
    int T)
{
    // Double-buffered staging; out-image overlays the buffer just computed.
    __shared__ __align__(16) float S[2][SFLOATS];  // 39,168 B
    __shared__ __align__(16) float Mf[TPB];        //     512 B
    __shared__ __align__(16) float Mb[TPB];        //     512 B
    __shared__ float Hb[NT][36];                   //     576 B => 40,768 B

    const int tid  = threadIdx.x;                // 0..127 (two waves)
    const int lane = tid & 63;
    const int wid  = tid >> 6;                   // 0: GEOM wave, 1: ANGLE wave
    const int h    = lane & 1;                   // hand side
    const int r    = lane >> 1;                  // record 0..31 within tile
    const int blocksPerRow = T / TPB;
    const int b    = blockIdx.x / blocksPerRow;
    const int tB   = (blockIdx.x - b * blocksPerRow) * TPB;  // block start t
    const int bT0  = b * T;

    const float* gb = xyz + (size_t)(bT0 + tB) * NC;

    // staging: 18 full 1KB chunks (9/wave) + 2x36-lane tail chunks (1/wave)
    // = exactly 10 unconditional-issue VMEM ops per wave per tile.
    auto stage_tile = [&](int k, float* Sd) {
        const float* g = gb + (size_t)k * SFLOATS;
        #pragma unroll
        for (int i = 0; i < 9; ++i) {
            const int j = 2 * i + wid;           // wave0 even, wave1 odd, 0..17
            dma16(g + j * 256 + lane * 4, Sd + j * 256);
        }
        const int f4b = 1152 + wid * 36;         // floats 4608..4895 split 36/36
        if (lane < 36)                           // exec-masked, always issues
            dma16(g + (f4b + lane) * 4, Sd + f4b * 4);
    };

    // ===== prologue: masks + all halos + tiles 0,1 (26 VMEM per wave) ======
    if (lane < 32) {                             // both waves duplicate: 2 ops
        dma16(fmask + (bT0 + tB) + lane * 4, Mf);
        dma16(bmask + (bT0 + tB) + lane * 4, Mb);
    }
    #pragma unroll
    for (int k = 0; k < NT; ++k) {               // 4 ops/wave (duplicated)
        if (lane < 36) {
            const int e = lane / 9, c = lane - e * 9;
            int tt = tB + k * TILE + (e < 2 ? e - 2 : TILE - 2 + e);
            tt = tt < 0 ? 0 : (tt > T - 1 ? T - 1 : tt);
            const int g3 = c / 3;
            dma4(xyz + (size_t)(bT0 + tt) * NC + g3 * 63 + (c - g3 * 3),
                 &Hb[k][0]);
        }
    }
    stage_tile(0, &S[0][0]);                     // 10 ops/wave
    stage_tile(1, &S[1][0]);                     // 10 ops/wave

    // ===== pipelined main loop over NT tiles ==============================
    #pragma unroll 1
    for (int k = 0; k < NT; ++k) {
        float* Sp = &S[k & 1][0];

        // wait: tile-k staging (+ older masks/halos) done; newer ops stay in
        // flight. Counts: k=0 -> t1(10); k=1,2 -> st(8)+tk+2(10)=18; k=3 -> 8.
        if (k == 0)
            asm volatile("s_waitcnt vmcnt(10) lgkmcnt(0)" ::: "memory");
        else if (k == NT - 1)
            asm volatile("s_waitcnt vmcnt(8) lgkmcnt(0)" ::: "memory");
        else
            asm volatile("s_waitcnt vmcnt(18) lgkmcnt(0)" ::: "memory");
        __builtin_amdgcn_sched_barrier(0);
        __builtin_amdgcn_s_barrier();            // raw barrier: no vm drain

        const int tk0 = tB + k * TILE;
        const int t   = tk0 + r;
        const float fg = Mf[k * TILE + r];
        const float bg = Mb[k * TILE + r];
        const float* Rec = Sp + r * NC;
        const float* R   = Rec + h * 63;
        auto PL = [&](int lm) -> V3 {
            int c = 3 * lm;
            return V3{R[c], R[c + 1], R[c + 2]};
        };

        // wave1 (ANGLE) outputs
        float cang[15];
        V3 nvec;
        float e0, e1, e2;
        // wave0 (GEOM) outputs
        float a0, a1, a2, a3, a4, a5, a6, a7, a8, a9, a10, a11, l1;
        float g0, g1, g2, h_turn, k_d, n_sp, o_acc;
        float b0, b1, b2, b3, b4;
        float q0, q1, q2, q3, q111, qm;
        float s88, s89, s90, s97, s102;

        if (wid == 1) {
            // --- Block C: joint angles (own hand) ---
            constexpr int TRI[15][3] = {
                {0, 1, 2},   {1, 2, 3},   {2, 3, 4},
                {0, 5, 6},   {5, 6, 7},   {6, 7, 8},
                {0, 9, 10},  {9, 10, 11}, {10, 11, 12},
                {0, 13, 14}, {13, 14, 15},{14, 15, 16},
                {0, 17, 18}, {17, 18, 19},{18, 19, 20}};
            #pragma unroll
            for (int i = 0; i < 15; ++i) {
                V3 pjv = PL(TRI[i][1]);
                V3 v1 = PL(TRI[i][0]) - pjv;
                V3 v2 = PL(TRI[i][2]) - pjv;
                cang[i] = acosc(dot3(v1, v2) * frcp(norm3(v1) * norm3(v2) + 1e-6f));
            }
            // --- Blocks D/F: palm normal ; Block E: spread (own hand) ---
            V3 w = PL(0);
            nvec = cross3(PL(5) - w, PL(17) - w);
            nvec = nvec * frcp(norm3(nvec) + 1e-6f);
            V3 v5  = PL(5)  - w;
            V3 v9  = PL(9)  - w;
            V3 v13 = PL(13) - w;
            V3 v17 = PL(17) - w;
            e0 = acosc(dot3(v5,  v9)  * frcp(norm3(v5)  * norm3(v9)  + 1e-6f));
            e1 = acosc(dot3(v9,  v13) * frcp(norm3(v9)  * norm3(v13) + 1e-6f));
            e2 = acosc(dot3(v13, v17) * frcp(norm3(v13) * norm3(v17) + 1e-6f));
        } else {
            // --- Block A: tips + curls + cross + d_ti (own hand) ---
            V3 t_tip = PL(4),  i_tip = PL(8),  m_tip = PL(12);
            V3 r_tip = PL(16), p_tip = PL(20);
            a0 = dist3(t_tip, i_tip);
            a1 = dist3(i_tip, m_tip);
            a2 = dist3(m_tip, r_tip);
            a3 = dist3(r_tip, p_tip);
            a4 = dist3(t_tip, p_tip);
            V3 tm = PL(2),  tjj = PL(3);
            a5 = dist3(tm, t_tip) * frcp(dist3(tm, tjj) + 1e-4f);
            V3 im = PL(5),  ijj = PL(6);
            a6 = dist3(im, i_tip) * frcp(dist3(im, ijj) + 1e-4f);
            V3 mm = PL(9),  mjj = PL(10);
            a7 = dist3(mm, m_tip) * frcp(dist3(mm, mjj) + 1e-4f);
            V3 rm = PL(13), rjj = PL(14);
            a8 = dist3(rm, r_tip) * frcp(dist3(rm, rjj) + 1e-4f);
            V3 pm = PL(17), pjj = PL(18);
            a9  = dist3(pm, p_tip) * frcp(dist3(pm, pjj) + 1e-4f);
            a10 = i_tip.x - m_tip.x;
            a11 = dist3(t_tip, im);
            l1  = m_tip.x - r_tip.x;

            // --- temporal: staging for rel in [0,32), Hb[k] edges otherwise
            auto HP = [&](int cb, int th) -> V3 {   // cb in {0,3,6}
                int rel = th - tk0;
                const float* q;
                if (rel >= 0 && rel < TILE) q = Sp + rel * NC + cb * 21;
                else q = &Hb[k][(rel < 0 ? rel + 2 : rel - (TILE - 2)) * 9 + cb];
                return V3{q[0], q[1], q[2]};
            };
            auto wvel = [&](int cb, int tt) -> V3 {
                int ta, tb; bmap(tt, T, ta, tb);
                return (HP(cb, tb) - HP(cb, ta)) * 0.5f;
            };
            auto wacc = [&](int cb, int tt) -> V3 {
                int ta, tb; bmap(tt, T, ta, tb);
                return (wvel(cb, tb) - wvel(cb, ta)) * 0.5f;
            };

            V3 velW0 = wvel(0, t), velW1 = wvel(3, t);
            V3 velOwn = {h ? velW1.x : velW0.x, h ? velW1.y : velW0.y,
                         h ? velW1.z : velW0.z};

            float g_inv = frcp(fmaxf(norm3(velOwn), 1e-6f));
            g0 = velOwn.x * g_inv; g1 = velOwn.y * g_inv; g2 = velOwn.z * g_inv;
            h_turn = 0.0f;
            if (t < T - 1) {
                V3 v1t = wvel(3 * h, t + 1);
                V3 aa = velOwn * frcp(norm3(velOwn) + 1e-6f);
                V3 cc = v1t * frcp(norm3(v1t) + 1e-6f);
                h_turn = acosc(dot3(aa, cc));
            }
            {
                int ta, tb; bmap(t, T, ta, tb);
                float da = norm3(HP(3 * h, ta) - HP(6, ta));
                float db = norm3(HP(3 * h, tb) - HP(6, tb));
                k_d = (db - da) * 0.5f;
            }
            n_sp  = norm3(velOwn);
            o_acc = norm3(wacc(3 * h, t));
            V3 p0h = HP(0, t), p21h = HP(3, t);
            s88 = dist3(p0h, p21h);
            V3 relv = p21h - p0h;
            float rinv = frcp(norm3(relv) + 1e-6f);
            s89 = relv.x * rinv; s90 = relv.y * rinv;
            V3 ldv = velW0 * frcp(norm3(velW0) + 1e-6f);
            V3 rdv = velW1 * frcp(norm3(velW1) + 1e-6f);
            s97 = dot3(ldv, rdv);
            float hd = norm3(p0h - p21h);
            s102 = frcp(1.0f + __expf(-5.0f * (0.05f - hd)));

            // --- face + body (own-wrist symmetric) ---
            V3 w = PL(0);
            auto FL = [&](int kk) -> V3 {           // landmark 42+kk
                const float* q = Rec + 126 + 3 * kk;
                return V3{q[0], q[1], q[2]};
            };
            V3 nose = FL(0), chin = FL(1), fore = FL(2);
            b0 = dist3(w, nose) * fg;
            b1 = dist3(w, chin) * fg;
            b2 = dist3(w, fore) * fg;
            b3 = dist3(i_tip, nose) * fg;
            b4 = dist3(i_tip, fore) * fg;
            V3 lsh = FL(3), rsh = FL(4);
            V3 shmid = (lsh + rsh) * 0.5f;
            float shw  = dist3(lsh, rsh);
            float invw = frcp(shw + 1e-6f);
            q0 = (w.y - shmid.y) * invw * bg;
            q1 = (w.x - shmid.x) * invw * bg;
            q2 = dist3(w, FL(3 + h)) * bg;          // own shoulder
            q3 = dist3(w, FL(5 + h)) * bg;          // own elbow
            q111 = shw * bg;
            V3 mouth = (FL(7) + FL(8)) * 0.5f;
            qm = dist3(w, mouth) * bg;
        }

        // all S[p] reads retired before the image overlays it
        asm volatile("s_waitcnt lgkmcnt(0)" ::: "memory");
        __builtin_amdgcn_sched_barrier(0);
        __builtin_amdgcn_s_barrier();

        {
            float* W = Sp + r * NF;                 // image row r
            if (wid == 1) {
                #pragma unroll
                for (int i = 0; i < 15; ++i) W[34 + 15 * h + i] = cang[i];
                W[64 + 3 * h] = nvec.x; W[65 + 3 * h] = nvec.y; W[66 + 3 * h] = nvec.z;
                W[76 + 2 * h] = nvec.y; W[77 + 2 * h] = nvec.z;
                W[70 + 3 * h] = e0; W[71 + 3 * h] = e1; W[72 + 3 * h] = e2;
            } else {
                W[12 * h + 0]  = a0;  W[12 * h + 1]  = a1;  W[12 * h + 2]  = a2;
                W[12 * h + 3]  = a3;  W[12 * h + 4]  = a4;  W[12 * h + 5]  = a5;
                W[12 * h + 6]  = a6;  W[12 * h + 7]  = a7;  W[12 * h + 8]  = a8;
                W[12 * h + 9]  = a9;  W[12 * h + 10] = a10; W[12 * h + 11] = a11;
                W[93 + 2 * h] = a10; W[94 + 2 * h] = l1;
                W[80 + 3 * h] = g0; W[81 + 3 * h] = g1; W[82 + 3 * h] = g2;
                W[86 + h]  = h_turn;
                W[91 + h]  = k_d;
                W[98 + h]  = n_sp;
                W[100 + h] = o_acc;
                W[24 + 3 * h] = b0; W[25 + 3 * h] = b1; W[26 + 3 * h] = b2;
                W[30 + 2 * h] = b3; W[31 + 2 * h] = b4;
                W[103 + 4 * h] = q0; W[104 + 4 * h] = q1;
                W[105 + 4 * h] = q2; W[106 + 4 * h] = q3;
                W[112 + h] = qm;
                if (h == 0) {
                    W[88] = s88; W[89] = s89; W[90] = s90;
                    W[102] = s102; W[111] = q111;
                } else {
                    W[97] = s97;
                }
            }
        }

        // image complete and visible
        asm volatile("s_waitcnt lgkmcnt(0)" ::: "memory");
        __builtin_amdgcn_sched_barrier(0);
        __builtin_amdgcn_s_barrier();

        // coalesced burst store: 912 float4 = 7*128 + 16; 8 stores per wave
        {
            float* dst = out + (size_t)(bT0 + tk0) * NF;
            #pragma unroll
            for (int i = 0; i < 7; ++i) {
                const int o4 = (i * 128 + tid) * 4;
                *reinterpret_cast<float4*>(dst + o4) =
                    *reinterpret_cast<const float4*>(Sp + o4);
            }
            if (lane < 8) {                         // exec-masked, always issues
                const int o4 = (896 + wid * 8 + lane) * 4;
                *reinterpret_cast<float4*>(dst + o4) =
                    *reinterpret_cast<const float4*>(Sp + o4);
            }
        }

        // both waves' LDS reads retired BEFORE reusing Sp for tile k+2 DMA
        asm volatile("s_waitcnt lgkmcnt(0)" ::: "memory");
        __builtin_amdgcn_sched_barrier(0);
        __builtin_amdgcn_s_barrier();

        if (k + 2 < NT)
            stage_tile(k + 2, Sp);                  // 10 ops/wave, stays in flight
        __builtin_amdgcn_sched_barrier(0);
    }
}

// ---------------------------------------------------------------------------
// Fallback: direct kernel (correct for any shape)
// ---------------------------------------------------------------------------
__constant__ int c_TRI[15][3] = {
    {0, 1, 2},   {1, 2, 3},   {2, 3, 4},
    {0, 5, 6},   {5, 6, 7},   {6, 7, 8},
    {0, 9, 10},  {9, 10, 11}, {10, 11, 12},
    {0, 13, 14}, {13, 14, 15},{14, 15, 16},
    {0, 17, 18}, {17, 18, 19},{18, 19, 20}};

__global__ __launch_bounds__(256) void geo_direct(
    const float* __restrict__ xyz,
    const float* __restrict__ fmask,
    const float* __restrict__ bmask,
    float* __restrict__ out,
    int BT, int T)
{
    int idx = blockIdx.x * blockDim.x + threadIdx.x;
    if (idx >= BT) return;
    int b = idx / T;
    int t = idx - b * T;
    int bT0 = b * T;

    auto ldp = [&](int tt, int lm) -> V3 {
        const float* p = xyz + ((size_t)(bT0 + tt) * 51 + (size_t)lm) * 3;
        return V3{p[0], p[1], p[2]};
    };
    auto P = [&](int lm) -> V3 { return ldp(t, lm); };
    auto velAt = [&](int lm, int tt) -> V3 {
        int ta, tb; bmap(tt, T, ta, tb);
        return (ldp(tb, lm) - ldp(ta, lm)) * 0.5f;
    };
    auto accAt = [&](int lm, int tt) -> V3 {
        int ta, tb; bmap(tt, T, ta, tb);
        return (velAt(lm, tb) - velAt(lm, ta)) * 0.5f;
    };

    float fg = fmask[idx];
    float bg = bmask[idx];
    float* o = out + (size_t)idx * NF;

    for (int h = 0; h < 2; ++h) {
        int base = h * 21;
        V3 t_tip = P(base + 4),  i_tip = P(base + 8),  m_tip = P(base + 12);
        V3 r_tip = P(base + 16), p_tip = P(base + 20);
        float* oa = o + h * 12;
        oa[0] = dist3(t_tip, i_tip);
        oa[1] = dist3(i_tip, m_tip);
        oa[2] = dist3(m_tip, r_tip);
        oa[3] = dist3(r_tip, p_tip);
        oa[4] = dist3(t_tip, p_tip);
        V3 tm = P(base + 2),  tj = P(base + 3);
        oa[5] = dist3(tm, t_tip) / (dist3(tm, tj) + 1e-4f);
        V3 im = P(base + 5),  ij = P(base + 6);
        oa[6] = dist3(im, i_tip) / (dist3(im, ij) + 1e-4f);
        V3 mm = P(base + 9),  mj = P(base + 10);
        oa[7] = dist3(mm, m_tip) / (dist3(mm, mj) + 1e-4f);
        V3 rm = P(base + 13), rj = P(base + 14);
        oa[8] = dist3(rm, r_tip) / (dist3(rm, rj) + 1e-4f);
        V3 pm = P(base + 17), pj = P(base + 18);
        oa[9] = dist3(pm, p_tip) / (dist3(pm, pj) + 1e-4f);
        oa[10] = i_tip.x - m_tip.x;
        oa[11] = dist3(t_tip, im);
    }

    V3 p0 = P(0), p21 = P(21);
    V3 nose = P(42), chin = P(43), fore = P(44);
    V3 itip0 = P(8), itip1 = P(29);
    o[24] = dist3(p0, nose) * fg;
    o[25] = dist3(p0, chin) * fg;
    o[26] = dist3(p0, fore) * fg;
    o[27] = dist3(p21, nose) * fg;
    o[28] = dist3(p21, chin) * fg;
    o[29] = dist3(p21, fore) * fg;
    o[30] = dist3(itip0, nose) * fg;
    o[31] = dist3(itip0, fore) * fg;
    o[32] = dist3(itip1, nose) * fg;
    o[33] = dist3(itip1, fore) * fg;

    for (int h = 0; h < 2; ++h) {
        int base = h * 21;
        for (int i = 0; i < 15; ++i) {
            V3 pj = P(base + c_TRI[i][1]);
            V3 v1 = P(base + c_TRI[i][0]) - pj;
            V3 v2 = P(base + c_TRI[i][2]) - pj;
            o[34 + h * 15 + i] = acosc(dot3(v1, v2) / (norm3(v1) * norm3(v2) + 1e-6f));
        }
    }

    V3 nrm[2];
    for (int h = 0; h < 2; ++h) {
        int base = h * 21;
        V3 w = (h == 0) ? p0 : p21;
        V3 n = cross3(P(base + 5) - w, P(base + 17) - w);
        float inv = 1.0f / (norm3(n) + 1e-6f);
        n = n * inv;
        nrm[h] = n;
        o[64 + 3 * h + 0] = n.x;
        o[64 + 3 * h + 1] = n.y;
        o[64 + 3 * h + 2] = n.z;
    }

    for (int h = 0; h < 2; ++h) {
        int base = h * 21;
        V3 w = (h == 0) ? p0 : p21;
        V3 v5  = P(base + 5)  - w;
        V3 v9  = P(base + 9)  - w;
        V3 v13 = P(base + 13) - w;
        V3 v17 = P(base + 17) - w;
        o[70 + 3 * h + 0] = acosc(dot3(v5,  v9)  / (norm3(v5)  * norm3(v9)  + 1e-6f));
        o[70 + 3 * h + 1] = acosc(dot3(v9,  v13) / (norm3(v9)  * norm3(v13) + 1e-6f));
        o[70 + 3 * h + 2] = acosc(dot3(v13, v17) / (norm3(v13) * norm3(v17) + 1e-6f));
    }

    for (int h = 0; h < 2; ++h) {
        o[76 + 2 * h + 0] = nrm[h].y;
        o[76 + 2 * h + 1] = nrm[h].z;
    }

    V3 velW[2];
    for (int h = 0; h < 2; ++h) {
        V3 v = velAt(h * 21, t);
        velW[h] = v;
        float inv = 1.0f / fmaxf(norm3(v), 1e-6f);
        o[80 + 3 * h + 0] = v.x * inv;
        o[80 + 3 * h + 1] = v.y * inv;
        o[80 + 3 * h + 2] = v.z * inv;
    }

    for (int h = 0; h < 2; ++h) {
        float val = 0.0f;
        if (t < T - 1) {
            V3 v0 = velW[h];
            V3 v1 = velAt(h * 21, t + 1);
            V3 a = v0 * (1.0f / (norm3(v0) + 1e-6f));
            V3 c = v1 * (1.0f / (norm3(v1) + 1e-6f));
            val = acosc(dot3(a, c));
        }
        o[86 + h] = val;
    }

    o[88] = dist3(p0, p21);
    {
        V3 rel = p21 - p0;
        float inv = 1.0f / (norm3(rel) + 1e-6f);
        o[89] = rel.x * inv;
        o[90] = rel.y * inv;
    }

    for (int h = 0; h < 2; ++h) {
        int lm = h * 21;
        int ta, tb; bmap(t, T, ta, tb);
        float da = norm3(ldp(ta, lm) - ldp(ta, 42));
        float db = norm3(ldp(tb, lm) - ldp(tb, 42));
        o[91 + h] = (db - da) * 0.5f;
    }

    for (int h = 0; h < 2; ++h) {
        int base = h * 21;
        float ix = P(base + 8).x, mx = P(base + 12).x, rx = P(base + 16).x;
        o[93 + 2 * h + 0] = ix - mx;
        o[93 + 2 * h + 1] = mx - rx;
    }

    {
        V3 ldv = velW[0] * (1.0f / (norm3(velW[0]) + 1e-6f));
        V3 rdv = velW[1] * (1.0f / (norm3(velW[1]) + 1e-6f));
        o[97] = dot3(ldv, rdv);
    }

    o[98] = norm3(velW[0]);
    o[99] = norm3(velW[1]);
    o[100] = norm3(accAt(0, t));
    o[101] = norm3(accAt(21, t));

    {
        float hd = norm3(p0 - p21);
        o[102] = 1.0f / (1.0f + expf(-5.0f * (0.05f - hd)));
    }

    {
        V3 lsh = P(45), rsh = P(46);
        V3 shmid = (lsh + rsh) * 0.5f;
        float shw = dist3(lsh, rsh);
        float invw = 1.0f / (shw + 1e-6f);
        o[103] = (p0.y - shmid.y) * invw * bg;
        o[104] = (p0.x - shmid.x) * invw * bg;
        o[105] = dist3(p0, lsh) * bg;
        o[106] = dist3(p0, P(47)) * bg;
        o[107] = (p21.y - shmid.y) * invw * bg;
        o[108] = (p21.x - shmid.x) * invw * bg;
        o[109] = dist3(p21, rsh) * bg;
        o[110] = dist3(p21, P(48)) * bg;
        o[111] = shw * bg;
        V3 mouth = (P(49) + P(50)) * 0.5f;
        o[112] = dist3(p0, mouth) * bg;
        o[113] = dist3(p21, mouth) * bg;
    }
}

extern "C" void kernel_launch(void* const* d_in, const int* in_sizes, int n_in,
                              void* d_out, int out_size, void* d_ws, size_t ws_size,
                              hipStream_t stream) {
    const float* xyz   = (const float*)d_in[0];
    const float* fmask = (const float*)d_in[1];
    const float* bmask = (const float*)d_in[2];
    float* out = (float*)d_out;

    const int BT = in_sizes[1];   // B*T (face_mask element count)
    const int T  = 512;           // per reference setup_inputs

    if (T % TPB == 0 && BT % T == 0) {
        // 1024 blocks x 128 threads; 40.8 KB LDS -> 4 blocks/CU = exactly
        // one generation (1024 = 256 CU x 4), counted-vmcnt pipelined.
        geo_fused<<<BT / TPB, 128, 0, stream>>>(xyz, fmask, bmask, out, T);
    } else {
        const int threads = 256;
        geo_direct<<<(BT + threads - 1) / threads, threads, 0, stream>>>(
            xyz, fmask, bmask, out, BT, T);
    }
}

// Round 9
// 139.146 us; speedup vs baseline: 1.0312x; 1.0312x over previous
//
#include <hip/hip_runtime.h>
#include <math.h>

// ---------------------------------------------------------------------------
// GeoFeatureExtractor: B=256, T=512, N=51 landmarks x 3 (fp32), 114 features.
// Round 14: staging-path A/B. Post-mortem of r6..r13: hbm_gbps pinned at
// 2.1-2.2 TB/s across EVERY structure (1-wave bulk-sync, 8-block, 16-wave
// role split, counted-vmcnt NT=4 pipeline) while fillBuffer streams 6.8 TB/s.
// The one invariant is global_load_lds staging. 2.2 TB/s = 8.6 GB/s/CU =
// ~8 x 1KB requests in flight per CU at ~900ns HBM latency -> behaves like a
// per-CU LDS-DMA queue depth cap. Occupancy/pipelining can't beat a per-CU
// FIFO — which is exactly why every structure landed at the same time.
// Change vs r11 (48.0 us baseline), ONE variable: staging becomes
// register-staged (global_load_dwordx4 -> VGPR -> ds_write_b128) with
// identical chunk coverage. Regular VMEM loads have per-wave MLP up to
// vmcnt=63 and no DMA FIFO.
// Everything else identical to r11: 128-thread blocks = 2 waves, ONE shared
// 32-record staging buffer, wave-uniform GEOM/ANGLE role split, LDS
// out-image overlay + coalesced float4 burst store, Hastings acos,
// __expf, v_rcp/v_sqrt, exact _cdiff boundary semantics. 19.7 KB LDS.
// ---------------------------------------------------------------------------

#define NF   114
#define NC   153
#define TILE 32                  // timesteps per block
#define SFLOATS (TILE * NC)      // 4896 floats staged linearly (19,584 B)

struct V3 { float x, y, z; };

__device__ __forceinline__ V3 operator-(V3 a, V3 b) { return {a.x - b.x, a.y - b.y, a.z - b.z}; }
__device__ __forceinline__ V3 operator+(V3 a, V3 b) { return {a.x + b.x, a.y + b.y, a.z + b.z}; }
__device__ __forceinline__ V3 operator*(V3 a, float s) { return {a.x * s, a.y * s, a.z * s}; }
__device__ __forceinline__ float dot3(V3 a, V3 b) { return a.x * b.x + a.y * b.y + a.z * b.z; }
__device__ __forceinline__ V3 cross3(V3 a, V3 b) {
    return {a.y * b.z - a.z * b.y, a.z * b.x - a.x * b.z, a.x * b.y - a.y * b.x};
}

__device__ __forceinline__ float fsqrt(float x) { return __builtin_amdgcn_sqrtf(x); }
__device__ __forceinline__ float frcp(float x)  { return __builtin_amdgcn_rcpf(x); }

__device__ __forceinline__ float norm3(V3 a) { return fsqrt(dot3(a, a)); }
__device__ __forceinline__ float dist3(V3 a, V3 b) { V3 d = a - b; return fsqrt(dot3(d, d) + 1e-6f); }

// clip + Hastings acos approximation, |err| < 7e-5 rad
__device__ __forceinline__ float acosc(float c) {
    c = fminf(fmaxf(c, -1.0f + 1e-6f), 1.0f - 1e-6f);
    float ax = fabsf(c);
    float r = fsqrt(1.0f - ax) *
              (1.5707288f + ax * (-0.2121144f + ax * (0.0742610f - 0.0187293f * ax)));
    return c < 0.0f ? 3.14159265358979f - r : r;
}

// boundary-mapped central-diff endpoints (exact _cdiff semantics)
__device__ __forceinline__ void bmap(int tt, int T, int& ta, int& tb) {
    if (tt == 0)          { ta = 0;      tb = 2;     }
    else if (tt == T - 1) { ta = T - 3;  tb = T - 1; }
    else                  { ta = tt - 1; tb = tt + 1; }
}

__global__ __launch_bounds__(128, 4) void geo_fused(
    const float* __restrict__ xyz,
    const float* __restrict__ fmask,
    const float* __restrict__ bmask,
    float* __restrict__ out,
    int T)
{
    // S: [staging] 32 records x 153 floats, linear (== global layout)
    //    [epilogue overlay] out-image 32 rows x 114 floats (14,592 B < 19,584)
    __shared__ __align__(16) float S[SFLOATS];   // 19,584 B
    __shared__ float Hb[36];                     //    144 B -> 8 blocks/CU

    const int tid  = threadIdx.x;                // 0..127 (two waves)
    const int lane = tid & 63;
    const int wid  = tid >> 6;                   // 0: GEOM wave, 1: ANGLE wave
    const int h    = lane & 1;                   // hand side
    const int r    = lane >> 1;                  // record 0..31
    const int tilesPerRow = T / TILE;
    const int b    = blockIdx.x / tilesPerRow;
    const int t0   = (blockIdx.x - b * tilesPerRow) * TILE;
    const int t    = t0 + r;
    const int bT0  = b * T;
    const int idx  = bT0 + t;

    const float* gbase = xyz + (size_t)(bT0 + t0) * NC;

    // ===== reg-staged copy: 19 full 1KB chunks + 128B tail, split across =====
    // waves (wave0 even chunks 0..18, wave1 odd 1..17 + tail). Loads issue
    // first (up to 10 dwordx4 in flight per wave, no DMA FIFO), ds_writes
    // after. Exact r8/r11 byte coverage; no OOB.
    float4 v0, v1, v2, v3, v4, v5, v6, v7, v8, v9;
    {
        const float* g = gbase + lane * 4;
        const int j0 = wid;                      // wid, wid+2, ..., wid+18
        v0 = *reinterpret_cast<const float4*>(g + (j0 +  0) * 256);
        v1 = *reinterpret_cast<const float4*>(g + (j0 +  2) * 256);
        v2 = *reinterpret_cast<const float4*>(g + (j0 +  4) * 256);
        v3 = *reinterpret_cast<const float4*>(g + (j0 +  6) * 256);
        v4 = *reinterpret_cast<const float4*>(g + (j0 +  8) * 256);
        v5 = *reinterpret_cast<const float4*>(g + (j0 + 10) * 256);
        v6 = *reinterpret_cast<const float4*>(g + (j0 + 12) * 256);
        v7 = *reinterpret_cast<const float4*>(g + (j0 + 14) * 256);
        v8 = *reinterpret_cast<const float4*>(g + (j0 + 16) * 256);
        if (wid == 0)                            // chunk 18 (wave0 only)
            v9 = *reinterpret_cast<const float4*>(g + 18 * 256);
        else if (lane < 8)                       // tail floats 4864..4895
            v9 = *reinterpret_cast<const float4*>(gbase + 19 * 256 + lane * 4);
    }

    // edge halo: 4 records (t0-2, t0-1, t0+TILE, t0+TILE+1) x 9 floats
    // per rec: {w0.xyz, w1.xyz, nose.xyz} at src offsets {0..2,63..65,126..128}
    float hreg = 0.0f;
    if (tid < 36) {
        int e = tid / 9, c = tid - e * 9;
        int th = t0 + (e < 2 ? e - 2 : TILE - 2 + e);
        th = th < 0 ? 0 : (th > T - 1 ? T - 1 : th);
        int g3 = c / 3;
        hreg = xyz[(size_t)(bT0 + th) * NC + g3 * 63 + (c - g3 * 3)];
    }

    float fg = 0.0f, bg = 0.0f;
    if (wid == 0) { fg = fmask[idx]; bg = bmask[idx]; }

    // ===== LDS writes (each waits only its own load via vmcnt counting) ====
    {
        float* d = S + lane * 4;
        const int j0 = wid;
        *reinterpret_cast<float4*>(d + (j0 +  0) * 256) = v0;
        *reinterpret_cast<float4*>(d + (j0 +  2) * 256) = v1;
        *reinterpret_cast<float4*>(d + (j0 +  4) * 256) = v2;
        *reinterpret_cast<float4*>(d + (j0 +  6) * 256) = v3;
        *reinterpret_cast<float4*>(d + (j0 +  8) * 256) = v4;
        *reinterpret_cast<float4*>(d + (j0 + 10) * 256) = v5;
        *reinterpret_cast<float4*>(d + (j0 + 12) * 256) = v6;
        *reinterpret_cast<float4*>(d + (j0 + 14) * 256) = v7;
        *reinterpret_cast<float4*>(d + (j0 + 16) * 256) = v8;
        if (wid == 0)
            *reinterpret_cast<float4*>(d + 18 * 256) = v9;
        else if (lane < 8)
            *reinterpret_cast<float4*>(S + 19 * 256 + lane * 4) = v9;
    }
    if (tid < 36) Hb[tid] = hreg;

    __syncthreads();   // all ds_writes visible

    // ===== compute (wave-uniform role split) ==============================
    const float* Rec = S + r * NC;               // this timestep's record
    const float* R   = Rec + h * 63;             // own hand base (0 or 63)
    auto PL = [&](int lm) -> V3 {
        int c = 3 * lm;
        return V3{R[c], R[c + 1], R[c + 2]};
    };

    // wave1 (ANGLE) outputs
    float cang[15];
    V3 nvec;
    float e0, e1, e2;
    // wave0 (GEOM) outputs
    float a0, a1, a2, a3, a4, a5, a6, a7, a8, a9, a10, a11, l1;
    float g0, g1, g2, h_turn, k_d, n_sp, o_acc;
    float b0, b1, b2, b3, b4;
    float q0, q1, q2, q3, q111, qm;
    float s88, s89, s90, s97, s102;

    if (wid == 1) {
        // --- Block C: joint angles (own hand) ---
        constexpr int TRI[15][3] = {
            {0, 1, 2},   {1, 2, 3},   {2, 3, 4},
            {0, 5, 6},   {5, 6, 7},   {6, 7, 8},
            {0, 9, 10},  {9, 10, 11}, {10, 11, 12},
            {0, 13, 14}, {13, 14, 15},{14, 15, 16},
            {0, 17, 18}, {17, 18, 19},{18, 19, 20}};
        #pragma unroll
        for (int i = 0; i < 15; ++i) {
            V3 pjv = PL(TRI[i][1]);
            V3 v1a = PL(TRI[i][0]) - pjv;
            V3 v2a = PL(TRI[i][2]) - pjv;
            cang[i] = acosc(dot3(v1a, v2a) * frcp(norm3(v1a) * norm3(v2a) + 1e-6f));
        }
        // --- Blocks D/F: palm normal ; Block E: spread (own hand) ---
        V3 w = PL(0);
        nvec = cross3(PL(5) - w, PL(17) - w);
        nvec = nvec * frcp(norm3(nvec) + 1e-6f);
        V3 w5  = PL(5)  - w;
        V3 w9  = PL(9)  - w;
        V3 w13 = PL(13) - w;
        V3 w17 = PL(17) - w;
        e0 = acosc(dot3(w5,  w9)  * frcp(norm3(w5)  * norm3(w9)  + 1e-6f));
        e1 = acosc(dot3(w9,  w13) * frcp(norm3(w9)  * norm3(w13) + 1e-6f));
        e2 = acosc(dot3(w13, w17) * frcp(norm3(w13) * norm3(w17) + 1e-6f));
    } else {
        // --- Block A: tips + curls + cross + d_ti (own hand) ---
        V3 t_tip = PL(4),  i_tip = PL(8),  m_tip = PL(12);
        V3 r_tip = PL(16), p_tip = PL(20);
        a0 = dist3(t_tip, i_tip);
        a1 = dist3(i_tip, m_tip);
        a2 = dist3(m_tip, r_tip);
        a3 = dist3(r_tip, p_tip);
        a4 = dist3(t_tip, p_tip);
        V3 tm = PL(2),  tjj = PL(3);
        a5 = dist3(tm, t_tip) * frcp(dist3(tm, tjj) + 1e-4f);
        V3 im = PL(5),  ijj = PL(6);
        a6 = dist3(im, i_tip) * frcp(dist3(im, ijj) + 1e-4f);
        V3 mm = PL(9),  mjj = PL(10);
        a7 = dist3(mm, m_tip) * frcp(dist3(mm, mjj) + 1e-4f);
        V3 rm = PL(13), rjj = PL(14);
        a8 = dist3(rm, r_tip) * frcp(dist3(rm, rjj) + 1e-4f);
        V3 pm = PL(17), pjj = PL(18);
        a9  = dist3(pm, p_tip) * frcp(dist3(pm, pjj) + 1e-4f);
        a10 = i_tip.x - m_tip.x;
        a11 = dist3(t_tip, im);
        l1  = m_tip.x - r_tip.x;

        // --- temporal: staging for rel in [0,32), Hb edges otherwise ---
        auto HP = [&](int cb, int th) -> V3 {    // cb in {0,3,6}: w0/w1/nose
            int rel = th - t0;
            const float* q;
            if (rel >= 0 && rel < TILE) q = S + rel * NC + cb * 21;
            else q = Hb + (rel < 0 ? rel + 2 : rel - (TILE - 2)) * 9 + cb;
            return V3{q[0], q[1], q[2]};
        };
        auto wvel = [&](int cb, int tt) -> V3 {
            int ta, tb; bmap(tt, T, ta, tb);
            return (HP(cb, tb) - HP(cb, ta)) * 0.5f;
        };
        auto wacc = [&](int cb, int tt) -> V3 {
            int ta, tb; bmap(tt, T, ta, tb);
            return (wvel(cb, tb) - wvel(cb, ta)) * 0.5f;
        };

        V3 velW0 = wvel(0, t), velW1 = wvel(3, t);
        V3 velOwn = {h ? velW1.x : velW0.x, h ? velW1.y : velW0.y,
                     h ? velW1.z : velW0.z};

        // G: velocity direction (jnp.maximum eps), own hand
        float g_inv = frcp(fmaxf(norm3(velOwn), 1e-6f));
        g0 = velOwn.x * g_inv; g1 = velOwn.y * g_inv; g2 = velOwn.z * g_inv;
        // H: velocity-turn angle (padded 0 at t = T-1), own hand
        h_turn = 0.0f;
        if (t < T - 1) {
            V3 v1t = wvel(3 * h, t + 1);
            V3 aa = velOwn * frcp(norm3(velOwn) + 1e-6f);
            V3 cc = v1t * frcp(norm3(v1t) + 1e-6f);
            h_turn = acosc(dot3(aa, cc));
        }
        // K: d/dt of dist(wrist, nose), own hand (plain norm, no eps)
        {
            int ta, tb; bmap(t, T, ta, tb);
            float da = norm3(HP(3 * h, ta) - HP(6, ta));
            float db = norm3(HP(3 * h, tb) - HP(6, tb));
            k_d = (db - da) * 0.5f;
        }
        // N: speed ; O: accel magnitude (own hand)
        n_sp  = norm3(velOwn);
        o_acc = norm3(wacc(3 * h, t));
        // shared scalars (both lanes compute; split on write)
        V3 p0h = HP(0, t), p21h = HP(3, t);
        s88 = dist3(p0h, p21h);
        V3 relv = p21h - p0h;
        float rinv = frcp(norm3(relv) + 1e-6f);
        s89 = relv.x * rinv; s90 = relv.y * rinv;
        V3 ldv = velW0 * frcp(norm3(velW0) + 1e-6f);
        V3 rdv = velW1 * frcp(norm3(velW1) + 1e-6f);
        s97 = dot3(ldv, rdv);
        float hd = norm3(p0h - p21h);
        s102 = frcp(1.0f + __expf(-5.0f * (0.05f - hd)));

        // --- face + body (own-wrist symmetric) ---
        V3 w = PL(0);
        auto FL = [&](int k) -> V3 {             // landmark 42+k
            const float* q = Rec + 126 + 3 * k;
            return V3{q[0], q[1], q[2]};
        };
        V3 nose = FL(0), chin = FL(1), fore = FL(2);
        b0 = dist3(w, nose) * fg;
        b1 = dist3(w, chin) * fg;
        b2 = dist3(w, fore) * fg;
        b3 = dist3(i_tip, nose) * fg;
        b4 = dist3(i_tip, fore) * fg;
        V3 lsh = FL(3), rsh = FL(4);
        V3 shmid = (lsh + rsh) * 0.5f;
        float shw  = dist3(lsh, rsh);
        float invw = frcp(shw + 1e-6f);
        q0 = (w.y - shmid.y) * invw * bg;
        q1 = (w.x - shmid.x) * invw * bg;
        q2 = dist3(w, FL(3 + h)) * bg;           // own shoulder
        q3 = dist3(w, FL(5 + h)) * bg;           // own elbow
        q111 = shw * bg;
        V3 mouth = (FL(7) + FL(8)) * 0.5f;
        qm = dist3(w, mouth) * bg;
    }

    // ===== out-image write (overlays staging; all S reads are done) ========
    __syncthreads();
    {
        float* W = S + r * NF;                   // image row r; cols by h/role
        if (wid == 1) {
            #pragma unroll
            for (int i = 0; i < 15; ++i) W[34 + 15 * h + i] = cang[i];
            W[64 + 3 * h] = nvec.x; W[65 + 3 * h] = nvec.y; W[66 + 3 * h] = nvec.z;
            W[76 + 2 * h] = nvec.y; W[77 + 2 * h] = nvec.z;
            W[70 + 3 * h] = e0; W[71 + 3 * h] = e1; W[72 + 3 * h] = e2;
        } else {
            W[12 * h + 0]  = a0;  W[12 * h + 1]  = a1;  W[12 * h + 2]  = a2;
            W[12 * h + 3]  = a3;  W[12 * h + 4]  = a4;  W[12 * h + 5]  = a5;
            W[12 * h + 6]  = a6;  W[12 * h + 7]  = a7;  W[12 * h + 8]  = a8;
            W[12 * h + 9]  = a9;  W[12 * h + 10] = a10; W[12 * h + 11] = a11;
            W[93 + 2 * h] = a10; W[94 + 2 * h] = l1;
            W[80 + 3 * h] = g0; W[81 + 3 * h] = g1; W[82 + 3 * h] = g2;
            W[86 + h]  = h_turn;
            W[91 + h]  = k_d;
            W[98 + h]  = n_sp;
            W[100 + h] = o_acc;
            W[24 + 3 * h] = b0; W[25 + 3 * h] = b1; W[26 + 3 * h] = b2;
            W[30 + 2 * h] = b3; W[31 + 2 * h] = b4;
            W[103 + 4 * h] = q0; W[104 + 4 * h] = q1;
            W[105 + 4 * h] = q2; W[106 + 4 * h] = q3;
            W[112 + h] = qm;
            if (h == 0) {
                W[88] = s88; W[89] = s89; W[90] = s90;
                W[102] = s102; W[111] = q111;
            } else {
                W[97] = s97;
            }
        }
    }
    __syncthreads();

    // ===== coalesced burst store: 32 x 456 B = 912 float4 = 7*128 + 16 =====
    {
        float* dst = out + (size_t)(bT0 + t0) * NF;
        #pragma unroll
        for (int i = 0; i < 7; ++i) {
            const int o4 = (i * 128 + tid) * 4;
            float4 vv = *reinterpret_cast<const float4*>(S + o4);
            *reinterpret_cast<float4*>(dst + o4) = vv;
        }
        if (tid < 16) {
            const int o4 = (7 * 128 + tid) * 4;
            float4 vv = *reinterpret_cast<const float4*>(S + o4);
            *reinterpret_cast<float4*>(dst + o4) = vv;
        }
    }
}

// ---------------------------------------------------------------------------
// Fallback: direct kernel (correct for any shape)
// ---------------------------------------------------------------------------
__constant__ int c_TRI[15][3] = {
    {0, 1, 2},   {1, 2, 3},   {2, 3, 4},
    {0, 5, 6},   {5, 6, 7},   {6, 7, 8},
    {0, 9, 10},  {9, 10, 11}, {10, 11, 12},
    {0, 13, 14}, {13, 14, 15},{14, 15, 16},
    {0, 17, 18}, {17, 18, 19},{18, 19, 20}};

__global__ __launch_bounds__(256) void geo_direct(
    const float* __restrict__ xyz,
    const float* __restrict__ fmask,
    const float* __restrict__ bmask,
    float* __restrict__ out,
    int BT, int T)
{
    int idx = blockIdx.x * blockDim.x + threadIdx.x;
    if (idx >= BT) return;
    int b = idx / T;
    int t = idx - b * T;
    int bT0 = b * T;

    auto ldp = [&](int tt, int lm) -> V3 {
        const float* p = xyz + ((size_t)(bT0 + tt) * 51 + (size_t)lm) * 3;
        return V3{p[0], p[1], p[2]};
    };
    auto P = [&](int lm) -> V3 { return ldp(t, lm); };
    auto velAt = [&](int lm, int tt) -> V3 {
        int ta, tb; bmap(tt, T, ta, tb);
        return (ldp(tb, lm) - ldp(ta, lm)) * 0.5f;
    };
    auto accAt = [&](int lm, int tt) -> V3 {
        int ta, tb; bmap(tt, T, ta, tb);
        return (velAt(lm, tb) - velAt(lm, ta)) * 0.5f;
    };

    float fg = fmask[idx];
    float bg = bmask[idx];
    float* o = out + (size_t)idx * NF;

    for (int h = 0; h < 2; ++h) {
        int base = h * 21;
        V3 t_tip = P(base + 4),  i_tip = P(base + 8),  m_tip = P(base + 12);
        V3 r_tip = P(base + 16), p_tip = P(base + 20);
        float* oa = o + h * 12;
        oa[0] = dist3(t_tip, i_tip);
        oa[1] = dist3(i_tip, m_tip);
        oa[2] = dist3(m_tip, r_tip);
        oa[3] = dist3(r_tip, p_tip);
        oa[4] = dist3(t_tip, p_tip);
        V3 tm = P(base + 2),  tj = P(base + 3);
        oa[5] = dist3(tm, t_tip) / (dist3(tm, tj) + 1e-4f);
        V3 im = P(base + 5),  ij = P(base + 6);
        oa[6] = dist3(im, i_tip) / (dist3(im, ij) + 1e-4f);
        V3 mm = P(base + 9),  mj = P(base + 10);
        oa[7] = dist3(mm, m_tip) / (dist3(mm, mj) + 1e-4f);
        V3 rm = P(base + 13), rj = P(base + 14);
        oa[8] = dist3(rm, r_tip) / (dist3(rm, rj) + 1e-4f);
        V3 pm = P(base + 17), pj = P(base + 18);
        oa[9] = dist3(pm, p_tip) / (dist3(pm, pj) + 1e-4f);
        oa[10] = i_tip.x - m_tip.x;
        oa[11] = dist3(t_tip, im);
    }

    V3 p0 = P(0), p21 = P(21);
    V3 nose = P(42), chin = P(43), fore = P(44);
    V3 itip0 = P(8), itip1 = P(29);
    o[24] = dist3(p0, nose) * fg;
    o[25] = dist3(p0, chin) * fg;
    o[26] = dist3(p0, fore) * fg;
    o[27] = dist3(p21, nose) * fg;
    o[28] = dist3(p21, chin) * fg;
    o[29] = dist3(p21, fore) * fg;
    o[30] = dist3(itip0, nose) * fg;
    o[31] = dist3(itip0, fore) * fg;
    o[32] = dist3(itip1, nose) * fg;
    o[33] = dist3(itip1, fore) * fg;

    for (int h = 0; h < 2; ++h) {
        int base = h * 21;
        for (int i = 0; i < 15; ++i) {
            V3 pj = P(base + c_TRI[i][1]);
            V3 v1 = P(base + c_TRI[i][0]) - pj;
            V3 v2 = P(base + c_TRI[i][2]) - pj;
            o[34 + h * 15 + i] = acosc(dot3(v1, v2) / (norm3(v1) * norm3(v2) + 1e-6f));
        }
    }

    V3 nrm[2];
    for (int h = 0; h < 2; ++h) {
        int base = h * 21;
        V3 w = (h == 0) ? p0 : p21;
        V3 n = cross3(P(base + 5) - w, P(base + 17) - w);
        float inv = 1.0f / (norm3(n) + 1e-6f);
        n = n * inv;
        nrm[h] = n;
        o[64 + 3 * h + 0] = n.x;
        o[64 + 3 * h + 1] = n.y;
        o[64 + 3 * h + 2] = n.z;
    }

    for (int h = 0; h < 2; ++h) {
        int base = h * 21;
        V3 w = (h == 0) ? p0 : p21;
        V3 v5  = P(base + 5)  - w;
        V3 v9  = P(base + 9)  - w;
        V3 v13 = P(base + 13) - w;
        V3 v17 = P(base + 17) - w;
        o[70 + 3 * h + 0] = acosc(dot3(v5,  v9)  / (norm3(v5)  * norm3(v9)  + 1e-6f));
        o[70 + 3 * h + 1] = acosc(dot3(v9,  v13) / (norm3(v9)  * norm3(v13) + 1e-6f));
        o[70 + 3 * h + 2] = acosc(dot3(v13, v17) / (norm3(v13) * norm3(v17) + 1e-6f));
    }

    for (int h = 0; h < 2; ++h) {
        o[76 + 2 * h + 0] = nrm[h].y;
        o[76 + 2 * h + 1] = nrm[h].z;
    }

    V3 velW[2];
    for (int h = 0; h < 2; ++h) {
        V3 v = velAt(h * 21, t);
        velW[h] = v;
        float inv = 1.0f / fmaxf(norm3(v), 1e-6f);
        o[80 + 3 * h + 0] = v.x * inv;
        o[80 + 3 * h + 1] = v.y * inv;
        o[80 + 3 * h + 2] = v.z * inv;
    }

    for (int h = 0; h < 2; ++h) {
        float val = 0.0f;
        if (t < T - 1) {
            V3 v0 = velW[h];
            V3 v1 = velAt(h * 21, t + 1);
            V3 a = v0 * (1.0f / (norm3(v0) + 1e-6f));
            V3 c = v1 * (1.0f / (norm3(v1) + 1e-6f));
            val = acosc(dot3(a, c));
        }
        o[86 + h] = val;
    }

    o[88] = dist3(p0, p21);
    {
        V3 rel = p21 - p0;
        float inv = 1.0f / (norm3(rel) + 1e-6f);
        o[89] = rel.x * inv;
        o[90] = rel.y * inv;
    }

    for (int h = 0; h < 2; ++h) {
        int lm = h * 21;
        int ta, tb; bmap(t, T, ta, tb);
        float da = norm3(ldp(ta, lm) - ldp(ta, 42));
        float db = norm3(ldp(tb, lm) - ldp(tb, 42));
        o[91 + h] = (db - da) * 0.5f;
    }

    for (int h = 0; h < 2; ++h) {
        int base = h * 21;
        float ix = P(base + 8).x, mx = P(base + 12).x, rx = P(base + 16).x;
        o[93 + 2 * h + 0] = ix - mx;
        o[93 + 2 * h + 1] = mx - rx;
    }

    {
        V3 ldv = velW[0] * (1.0f / (norm3(velW[0]) + 1e-6f));
        V3 rdv = velW[1] * (1.0f / (norm3(velW[1]) + 1e-6f));
        o[97] = dot3(ldv, rdv);
    }

    o[98] = norm3(velW[0]);
    o[99] = norm3(velW[1]);
    o[100] = norm3(accAt(0, t));
    o[101] = norm3(accAt(21, t));

    {
        float hd = norm3(p0 - p21);
        o[102] = 1.0f / (1.0f + expf(-5.0f * (0.05f - hd)));
    }

    {
        V3 lsh = P(45), rsh = P(46);
        V3 shmid = (lsh + rsh) * 0.5f;
        float shw = dist3(lsh, rsh);
        float invw = 1.0f / (shw + 1e-6f);
        o[103] = (p0.y - shmid.y) * invw * bg;
        o[104] = (p0.x - shmid.x) * invw * bg;
        o[105] = dist3(p0, lsh) * bg;
        o[106] = dist3(p0, P(47)) * bg;
        o[107] = (p21.y - shmid.y) * invw * bg;
        o[108] = (p21.x - shmid.x) * invw * bg;
        o[109] = dist3(p21, rsh) * bg;
        o[110] = dist3(p21, P(48)) * bg;
        o[111] = shw * bg;
        V3 mouth = (P(49) + P(50)) * 0.5f;
        o[112] = dist3(p0, mouth) * bg;
        o[113] = dist3(p21, mouth) * bg;
    }
}

extern "C" void kernel_launch(void* const* d_in, const int* in_sizes, int n_in,
                              void* d_out, int out_size, void* d_ws, size_t ws_size,
                              hipStream_t stream) {
    const float* xyz   = (const float*)d_in[0];
    const float* fmask = (const float*)d_in[1];
    const float* bmask = (const float*)d_in[2];
    float* out = (float*)d_out;

    const int BT = in_sizes[1];   // B*T (face_mask element count)
    const int T  = 512;           // per reference setup_inputs

    if (T % TILE == 0 && BT % T == 0) {
        // 4096 blocks x 2 waves (role-split); 19.7 KB LDS -> 8 blocks/CU,
        // reg-staged loads (no global_load_lds anywhere).
        geo_fused<<<BT / TILE, 128, 0, stream>>>(xyz, fmask, bmask, out, T);
    } else {
        const int threads = 256;
        geo_direct<<<(BT + threads - 1) / threads, threads, 0, stream>>>(
            xyz, fmask, bmask, out, BT, T);
    }
}